// Round 6
// baseline (430.550 us; speedup 1.0000x reference)
//
#include <hip/hip_runtime.h>
#include <hip/hip_bf16.h>
#include <math.h>

#define Dm 1024
#define Hn 16
#define HDm 64
#define FFm 4096
#define Sn 2048
#define SEG 512
#define EPSV 1e-6f

typedef __attribute__((ext_vector_type(4))) float f32x4;
typedef __attribute__((ext_vector_type(8))) short s16x8;
typedef __attribute__((ext_vector_type(4))) short s16x4;

__device__ inline short f2bf(float f) {
  __hip_bfloat16 h = __float2bfloat16(f);
  short s;
  __builtin_memcpy(&s, &h, 2);
  return s;
}

__device__ inline float wred_sum(float v) {
#pragma unroll
  for (int m = 32; m > 0; m >>= 1) v += __shfl_xor(v, m, 64);
  return v;
}
__device__ inline float wred_max(float v) {
#pragma unroll
  for (int m = 32; m > 0; m >>= 1) v = fmaxf(v, __shfl_xor(v, m, 64));
  return v;
}

// async global->LDS, 16B per lane. LDS dest is wave-uniform base + lane*16.
__device__ inline void gld16(const short* g, short* lds_base) {
  __builtin_amdgcn_global_load_lds(
      (const __attribute__((address_space(1))) void*)g,
      (__attribute__((address_space(3))) void*)lds_base, 16, 0, 0);
}

// ---------------- LayerNorm: fp32 in -> bf16 out ----------------
__global__ __launch_bounds__(256) void ln_kernel(const float* __restrict__ x,
                                                 const float* __restrict__ g,
                                                 const float* __restrict__ b,
                                                 short* __restrict__ out) {
  const int row = blockIdx.x;
  const int tid = threadIdx.x;
  f32x4 v = *reinterpret_cast<const f32x4*>(x + (size_t)row * Dm + tid * 4);
  float s1 = v.x + v.y + v.z + v.w;
  float s2 = v.x * v.x + v.y * v.y + v.z * v.z + v.w * v.w;
  s1 = wred_sum(s1);
  s2 = wred_sum(s2);
  __shared__ float t1[4], t2[4];
  if ((tid & 63) == 0) { t1[tid >> 6] = s1; t2[tid >> 6] = s2; }
  __syncthreads();
  s1 = t1[0] + t1[1] + t1[2] + t1[3];
  s2 = t2[0] + t2[1] + t2[2] + t2[3];
  const float mean = s1 * (1.0f / Dm);
  const float var = s2 * (1.0f / Dm) - mean * mean;
  const float rstd = rsqrtf(var + EPSV);
  f32x4 gv = *reinterpret_cast<const f32x4*>(g + tid * 4);
  f32x4 bv = *reinterpret_cast<const f32x4*>(b + tid * 4);
  s16x4 o;
#pragma unroll
  for (int j = 0; j < 4; ++j)
    o[j] = f2bf((v[j] - mean) * rstd * gv[j] + bv[j]);
  *reinterpret_cast<s16x4*>(out + (size_t)row * Dm + tid * 4) = o;
}

// ---- fused split-K reduce + residual + LayerNorm ----
// xout = sum_s pb[s] + bias + res ; h = LN(xout)*g + b  (bf16)
template <int SPLIT>
__global__ __launch_bounds__(256) void redln_kernel(const float* __restrict__ pb,
                                                    const float* __restrict__ bias,
                                                    const float* __restrict__ res,
                                                    const float* __restrict__ g,
                                                    const float* __restrict__ b,
                                                    float* __restrict__ xout,
                                                    short* __restrict__ h) {
  const int row = blockIdx.x;
  const int tid = threadIdx.x;
  const size_t idx = (size_t)row * Dm + tid * 4;
  f32x4 o = *reinterpret_cast<const f32x4*>(res + idx);
  o += *reinterpret_cast<const f32x4*>(bias + tid * 4);
#pragma unroll
  for (int s = 0; s < SPLIT; ++s)
    o += *reinterpret_cast<const f32x4*>(pb + (size_t)s * Sn * Dm + idx);
  *reinterpret_cast<f32x4*>(xout + idx) = o;
  float s1 = o.x + o.y + o.z + o.w;
  float s2 = o.x * o.x + o.y * o.y + o.z * o.z + o.w * o.w;
  s1 = wred_sum(s1);
  s2 = wred_sum(s2);
  __shared__ float t1[4], t2[4];
  if ((tid & 63) == 0) { t1[tid >> 6] = s1; t2[tid >> 6] = s2; }
  __syncthreads();
  s1 = t1[0] + t1[1] + t1[2] + t1[3];
  s2 = t2[0] + t2[1] + t2[2] + t2[3];
  const float mean = s1 * (1.0f / Dm);
  const float var = s2 * (1.0f / Dm) - mean * mean;
  const float rstd = rsqrtf(var + EPSV);
  f32x4 gv = *reinterpret_cast<const f32x4*>(g + tid * 4);
  f32x4 bv = *reinterpret_cast<const f32x4*>(b + tid * 4);
  s16x4 ho;
#pragma unroll
  for (int j = 0; j < 4; ++j)
    ho[j] = f2bf((o[j] - mean) * rstd * gv[j] + bv[j]);
  *reinterpret_cast<s16x4*>(h + idx) = ho;
}

// ---- final split-K reduce: out = sum(partials) + bias + res (fp32) ----
template <int SPLIT>
__global__ __launch_bounds__(256) void fcred_kernel(const float* __restrict__ pb,
                                                    const float* __restrict__ bias,
                                                    const float* __restrict__ res,
                                                    float* __restrict__ out) {
  const size_t i = ((size_t)blockIdx.x * 256 + threadIdx.x) * 4;
  f32x4 o = *reinterpret_cast<const f32x4*>(res + i);
  o += *reinterpret_cast<const f32x4*>(bias + (i & (Dm - 1)));
#pragma unroll
  for (int s = 0; s < SPLIT; ++s)
    o += *reinterpret_cast<const f32x4*>(pb + (size_t)s * Sn * Dm + i);
  *reinterpret_cast<f32x4*>(out + i) = o;
}

// ---- FC1 reduce: ffn = gelu(p0 + p1 + bias)  (bf16) ----
__global__ __launch_bounds__(256) void fc1red_kernel(const float* __restrict__ pb,
                                                     const float* __restrict__ bias,
                                                     short* __restrict__ out) {
  const size_t i = ((size_t)blockIdx.x * 256 + threadIdx.x) * 4;
  f32x4 o = *reinterpret_cast<const f32x4*>(pb + i);
  o += *reinterpret_cast<const f32x4*>(pb + (size_t)Sn * FFm + i);
  o += *reinterpret_cast<const f32x4*>(bias + (i & (FFm - 1)));
  s16x4 s;
#pragma unroll
  for (int j = 0; j < 4; ++j) {
    float v = o[j];
    s[j] = f2bf(0.5f * v * (1.0f + erff(v * 0.70710678118654752f)));
  }
  *reinterpret_cast<s16x4*>(out + i) = s;
}

// ---- QKV reduce + bias + RoPE: fp32 partials -> bf16 qkv (q,k roped) ----
__global__ __launch_bounds__(256) void qkvred_kernel(const float* __restrict__ pb,
                                                     const float* __restrict__ bias,
                                                     const float* __restrict__ cosb,
                                                     const float* __restrict__ sinb,
                                                     short* __restrict__ qkv) {
  const int row = blockIdx.x;
  const int t = threadIdx.x;
  const size_t P1 = (size_t)Sn * 3 * Dm;
  const size_t rb = (size_t)row * 3 * Dm;
  // q,k region: 32 blocks of 64 cols; thread t -> block t>>3, quad (t&7)*4
  {
    const int col0 = (t >> 3) * 64 + (t & 7) * 4;
    const int col1 = col0 + 32;
    const int d0 = (t & 7) * 4;
    f32x4 a = *reinterpret_cast<const f32x4*>(pb + rb + col0);
    a += *reinterpret_cast<const f32x4*>(pb + P1 + rb + col0);
    a += *reinterpret_cast<const f32x4*>(bias + col0);
    f32x4 c2 = *reinterpret_cast<const f32x4*>(pb + rb + col1);
    c2 += *reinterpret_cast<const f32x4*>(pb + P1 + rb + col1);
    c2 += *reinterpret_cast<const f32x4*>(bias + col1);
    f32x4 cs0 = *reinterpret_cast<const f32x4*>(cosb + (size_t)row * HDm + d0);
    f32x4 sn0 = *reinterpret_cast<const f32x4*>(sinb + (size_t)row * HDm + d0);
    f32x4 cs1 = *reinterpret_cast<const f32x4*>(cosb + (size_t)row * HDm + d0 + 32);
    f32x4 sn1 = *reinterpret_cast<const f32x4*>(sinb + (size_t)row * HDm + d0 + 32);
    s16x4 o0, o1;
#pragma unroll
    for (int j = 0; j < 4; ++j) {
      o0[j] = f2bf(a[j] * cs0[j] - c2[j] * sn0[j]);
      o1[j] = f2bf(c2[j] * cs1[j] + a[j] * sn1[j]);
    }
    *reinterpret_cast<s16x4*>(qkv + rb + col0) = o0;
    *reinterpret_cast<s16x4*>(qkv + rb + col1) = o1;
  }
  // v region: cols 2048..3071
  {
    const int cv = 2048 + t * 4;
    f32x4 a = *reinterpret_cast<const f32x4*>(pb + rb + cv);
    a += *reinterpret_cast<const f32x4*>(pb + P1 + rb + cv);
    a += *reinterpret_cast<const f32x4*>(bias + cv);
    s16x4 o;
#pragma unroll
    for (int j = 0; j < 4; ++j) o[j] = f2bf(a[j]);
    *reinterpret_cast<s16x4*>(qkv + rb + cv) = o;
  }
}

// -------- softmax over 512-length rows; fp32 in -> compact bf16 probs --------
__global__ __launch_bounds__(128) void softmax_kernel(const float* __restrict__ scores,
                                                      short* __restrict__ probs) {
  const size_t rowoff = ((size_t)blockIdx.y * SEG + blockIdx.x) * SEG;
  const float* rp = scores + rowoff;
  const int tid = threadIdx.x;
  f32x4 v = *reinterpret_cast<const f32x4*>(rp + tid * 4);
  float mx = fmaxf(fmaxf(v.x, v.y), fmaxf(v.z, v.w));
  mx = wred_max(mx);
  __shared__ float rmax[2], rsum[2];
  if ((tid & 63) == 0) rmax[tid >> 6] = mx;
  __syncthreads();
  mx = fmaxf(rmax[0], rmax[1]);
  f32x4 e;
#pragma unroll
  for (int j = 0; j < 4; ++j) e[j] = __expf(v[j] - mx);
  float sm = e.x + e.y + e.z + e.w;
  sm = wred_sum(sm);
  if ((tid & 63) == 0) rsum[tid >> 6] = sm;
  __syncthreads();
  const float inv = 1.0f / (rsum[0] + rsum[1]);
  s16x4 o;
#pragma unroll
  for (int j = 0; j < 4; ++j) o[j] = f2bf(e[j] * inv);
  *reinterpret_cast<s16x4*>(probs + rowoff + tid * 4) = o;
}

// ---- transpose + convert: W (K x N fp32, row stride ldw) -> Wt (N x K bf16) ----
__global__ __launch_bounds__(256) void wt_kernel(const float* __restrict__ W,
                                                 short* __restrict__ Wt,
                                                 int K, int N, int ldw) {
  __shared__ float t[32][33];
  const int n0 = blockIdx.x * 32, k0 = blockIdx.y * 32;
  const int tx = threadIdx.x & 31, ty = threadIdx.x >> 5;  // ty 0..7
#pragma unroll
  for (int r = 0; r < 32; r += 8)
    t[r + ty][tx] = W[(size_t)(k0 + r + ty) * ldw + n0 + tx];
  __syncthreads();
#pragma unroll
  for (int r = 0; r < 32; r += 8)
    Wt[(size_t)(n0 + r + ty) * K + k0 + tx] = f2bf(t[tx][r + ty]);
}

// ---- bf16 transpose: V (K x N bf16, row stride ldv) -> Vt (N x K bf16) ----
__global__ __launch_bounds__(256) void wtb_kernel(const short* __restrict__ V,
                                                  short* __restrict__ Vt,
                                                  int K, int N, int ldv) {
  __shared__ short t[32][34];
  const int n0 = blockIdx.x * 32, k0 = blockIdx.y * 32;
  const int tx = threadIdx.x & 31, ty = threadIdx.x >> 5;
#pragma unroll
  for (int r = 0; r < 32; r += 8)
    t[r + ty][tx] = V[(size_t)(k0 + r + ty) * ldv + n0 + tx];
  __syncthreads();
#pragma unroll
  for (int r = 0; r < 32; r += 8)
    Vt[(size_t)(n0 + r + ty) * K + k0 + tx] = t[tx][r + ty];
}

// ---------------- GEMM: C = A (MxK) * Bt^T (Bt is NxK) ----------------
// m97 structure: single-buffered BK=64, 256 threads (4 waves), global_load_lds
// with XOR-swizzled source (linear LDS) + swizzled ds_read (zero conflicts).
// MODE 1: QK^T batched (fp32*scale out). MODE 2: PV batched (bf16 out).
// MODE 3: dense split-K (fp32 partials, z = split index).
struct GemmArgs {
  const short* A; int lda;
  const short* B; int ldb;
  void* C; int ldc;
  int M, N, K;
  float scale;
};

template <int BM, int BN, int SPLIT, int MODE>
__global__ __launch_bounds__(256) void gemm6(GemmArgs p) {
  constexpr int WN = 2;
  constexpr int WM = 2;
  constexpr int FI = BM / WM / 16;
  constexpr int FJ = BN / WN / 16;
  const int z = blockIdx.z;
  const short* A = p.A;
  const short* B = p.B;
  char* Cb = (char*)p.C;
  int kbase = 0, nkt = p.K >> 6;
  if (MODE == 1) {
    const int seg = z & 3, hh = z >> 2;
    A += (size_t)(seg * SEG) * p.lda + hh * HDm;
    B += (size_t)(seg * SEG) * p.ldb + hh * HDm;
    Cb += (size_t)z * SEG * SEG * 4;
  } else if (MODE == 2) {
    const int seg = z & 3, hh = z >> 2;
    A += (size_t)z * SEG * SEG;                    // compact probs, lda=512
    B += (size_t)(hh * HDm) * p.ldb + seg * SEG;   // vT slice
    Cb += ((size_t)seg * SEG * Dm + (size_t)hh * HDm) * 2;
  } else if (MODE == 3) {
    kbase = z * (p.K / SPLIT);
    nkt = (p.K / SPLIT) >> 6;
    Cb += (size_t)z * p.M * p.N * 4;
  }
  __shared__ short As[BM * 64];
  __shared__ short Bs[BN * 64];
  const int tid = threadIdx.x;
  const int lane = tid & 63;
  const int wave = tid >> 6;
  const int tileM = blockIdx.y * BM;
  const int tileN = blockIdx.x * BN;
  const int l15 = lane & 15;
  const int lg = lane >> 4;
  const int rx = l15 & 7;              // read-side swizzle key
  const int wr = (wave / WN) * (BM / WM);
  const int wc = (wave % WN) * (BN / WN);
  const int srow = lane >> 3;                      // 0..7
  const int scol = ((lane & 7) ^ srow) * 8;        // swizzled source chunk

  f32x4 acc[FI][FJ] = {};

  const short* Ag = A + (size_t)(tileM + wave * 8 + srow) * p.lda + scol + kbase;
  const short* Bg = B + (size_t)(tileN + wave * 8 + srow) * p.ldb + scol + kbase;

  for (int kt = 0; kt < nkt; ++kt) {
    const int k0 = kt * 64;
#pragma unroll
    for (int j = 0; j < BM / 32; ++j)
      gld16(Ag + (size_t)(j * 32) * p.lda + k0, &As[(j * 32 + wave * 8) * 64]);
#pragma unroll
    for (int j = 0; j < BN / 32; ++j)
      gld16(Bg + (size_t)(j * 32) * p.ldb + k0, &Bs[(j * 32 + wave * 8) * 64]);
    __syncthreads();
#pragma unroll
    for (int kk = 0; kk < 64; kk += 32) {
      const int kkc = kk >> 3;  // chunk base: 0 or 4
      s16x8 af[FI], bfr[FJ];
#pragma unroll
      for (int f = 0; f < FI; ++f)
        af[f] = *reinterpret_cast<const s16x8*>(
            &As[(wr + f * 16 + l15) * 64 + (((lg + kkc) ^ rx) << 3)]);
#pragma unroll
      for (int f = 0; f < FJ; ++f)
        bfr[f] = *reinterpret_cast<const s16x8*>(
            &Bs[(wc + f * 16 + l15) * 64 + (((lg + kkc) ^ rx) << 3)]);
#pragma unroll
      for (int fi = 0; fi < FI; ++fi)
#pragma unroll
        for (int fj = 0; fj < FJ; ++fj)
          acc[fi][fj] = __builtin_amdgcn_mfma_f32_16x16x32_bf16(
              af[fi], bfr[fj], acc[fi][fj], 0, 0, 0);
    }
    __syncthreads();
  }

#pragma unroll
  for (int fi = 0; fi < FI; ++fi) {
#pragma unroll
    for (int fj = 0; fj < FJ; ++fj) {
#pragma unroll
      for (int r = 0; r < 4; ++r) {
        const int row = tileM + wr + fi * 16 + lg * 4 + r;
        const int col = tileN + wc + fj * 16 + l15;
        const float v = acc[fi][fj][r] * p.scale;
        if (MODE == 2)
          reinterpret_cast<short*>(Cb)[(size_t)row * p.ldc + col] = f2bf(v);
        else
          reinterpret_cast<float*>(Cb)[(size_t)row * p.ldc + col] = v;
      }
    }
  }
}

extern "C" void kernel_launch(void* const* d_in, const int* in_sizes, int n_in,
                              void* d_out, int out_size, void* d_ws, size_t ws_size,
                              hipStream_t stream) {
  const float* x0 = (const float*)d_in[0];
  const float* cosb = (const float*)d_in[2];
  const float* sinb = (const float*)d_in[3];
  const float* ln1_g = (const float*)d_in[4];
  const float* ln1_b = (const float*)d_in[5];
  const float* qkv_w = (const float*)d_in[6];
  const float* qkv_b = (const float*)d_in[7];
  const float* proj_w = (const float*)d_in[8];
  const float* proj_b = (const float*)d_in[9];
  const float* ln2_g = (const float*)d_in[10];
  const float* ln2_b = (const float*)d_in[11];
  const float* fc1_w = (const float*)d_in[12];
  const float* fc1_b = (const float*)d_in[13];
  const float* fc2_w = (const float*)d_in[14];
  const float* fc2_b = (const float*)d_in[15];

  char* ws = (char*)d_ws;
  size_t off = 0;
  auto alloc = [&](size_t bytes) {
    void* p = ws + off;
    off += (bytes + 255) & ~(size_t)255;
    return p;
  };
  short* wqkvT = (short*)alloc((size_t)2 * 3072 * 1024 * 2);
  short* wprojT = (short*)alloc((size_t)2 * 1024 * 1024 * 2);
  short* wfc1T = (short*)alloc((size_t)2 * 4096 * 1024 * 2);
  short* wfc2T = (short*)alloc((size_t)2 * 1024 * 4096 * 2);
  float* xbuf = (float*)alloc((size_t)Sn * Dm * 4);
  short* hbuf = (short*)alloc((size_t)Sn * Dm * 2);
  short* qkvb = (short*)alloc((size_t)Sn * 3 * Dm * 2);   // q,k roped + v (bf16)
  short* probs = (short*)alloc((size_t)64 * SEG * SEG * 2);
  // scores fp32 (67MB). Also reused as split-K partial space (<=67MB) for
  // QKV (50MB), proj (17MB), FC1 (67MB), FC2 (67MB) — all disjoint lifetimes.
  float* scores = (float*)alloc((size_t)64 * SEG * SEG * 4);
  float* pbuf = scores;
  short* ao = (short*)alloc((size_t)Sn * Dm * 2);
  short* ffn = (short*)alloc((size_t)Sn * FFm * 2);
  short* vT = ffn;  // vT (4.2MB) aliases ffn: dead during attention phase
  (void)ws_size; (void)in_sizes; (void)n_in; (void)out_size;

  // weight transpose+convert (per call; stateless)
  for (int i = 0; i < 2; ++i) {
    wt_kernel<<<dim3(96, 32), 256, 0, stream>>>(
        qkv_w + (size_t)i * Dm * 3072, wqkvT + (size_t)i * 3072 * Dm, Dm, 3072, 3072);
    wt_kernel<<<dim3(32, 32), 256, 0, stream>>>(
        proj_w + (size_t)i * Dm * Dm, wprojT + (size_t)i * Dm * Dm, Dm, Dm, Dm);
    wt_kernel<<<dim3(128, 32), 256, 0, stream>>>(
        fc1_w + (size_t)i * Dm * FFm, wfc1T + (size_t)i * FFm * Dm, Dm, FFm, FFm);
    wt_kernel<<<dim3(32, 128), 256, 0, stream>>>(
        fc2_w + (size_t)i * FFm * Dm, wfc2T + (size_t)i * Dm * FFm, FFm, Dm, Dm);
  }

  // layer 0 LN1
  ln_kernel<<<dim3(Sn), 256, 0, stream>>>(x0, ln1_g, ln1_b, hbuf);

  for (int i = 0; i < 2; ++i) {
    const float* xin = i ? (const float*)xbuf : x0;

    {  // qkv partials = h @ Wqkv  (split-K=2, fp32)
      GemmArgs p = {};
      p.A = hbuf; p.lda = Dm;
      p.B = wqkvT + (size_t)i * 3072 * Dm; p.ldb = Dm;
      p.C = pbuf; p.ldc = 3 * Dm;
      p.M = Sn; p.N = 3 * Dm; p.K = Dm; p.scale = 1.0f;
      gemm6<128, 128, 2, 3><<<dim3(24, 16, 2), 256, 0, stream>>>(p);
    }
    // qkvb = rope(p0+p1+bias) for q,k ; plain for v  (bf16)
    qkvred_kernel<<<dim3(Sn), 256, 0, stream>>>(pbuf, qkv_b + i * 3 * Dm,
                                                cosb, sinb, qkvb);

    // v (bf16 cols 2048.. of qkvb) -> vT (coalesced LDS-tiled transpose)
    wtb_kernel<<<dim3(32, 64), 256, 0, stream>>>(qkvb + 2 * Dm, vT, Sn, Dm, 3 * Dm);

    {  // scores = scale * q @ k^T  per (head, seg)  (fp32 out)
      GemmArgs p = {};
      p.A = qkvb; p.lda = 3 * Dm;
      p.B = qkvb + Dm; p.ldb = 3 * Dm;
      p.C = scores; p.ldc = SEG;
      p.M = SEG; p.N = SEG; p.K = HDm; p.scale = 0.125f;
      gemm6<128, 128, 1, 1><<<dim3(4, 4, 64), 256, 0, stream>>>(p);
    }

    softmax_kernel<<<dim3(SEG, 64), 128, 0, stream>>>(scores, probs);

    {  // ao = probs @ V  per (head, seg)  (bf16 out)
      GemmArgs p = {};
      p.A = probs; p.lda = SEG;
      p.B = vT; p.ldb = Sn;
      p.C = ao; p.ldc = Dm;
      p.M = SEG; p.N = HDm; p.K = SEG; p.scale = 1.0f;
      gemm6<64, 64, 1, 2><<<dim3(1, 8, 64), 256, 0, stream>>>(p);
    }

    {  // proj partials = ao @ Wproj  (split-K=2, fp32)
      GemmArgs p = {};
      p.A = ao; p.lda = Dm;
      p.B = wprojT + (size_t)i * Dm * Dm; p.ldb = Dm;
      p.C = pbuf; p.ldc = Dm;
      p.M = Sn; p.N = Dm; p.K = Dm; p.scale = 1.0f;
      gemm6<64, 64, 2, 3><<<dim3(16, 32, 2), 256, 0, stream>>>(p);
    }
    // x = xin + proj + bias ; h = LN2(x)
    redln_kernel<2><<<dim3(Sn), 256, 0, stream>>>(
        pbuf, proj_b + i * Dm, xin, ln2_g + i * Dm, ln2_b + i * Dm, xbuf, hbuf);

    {  // fc1 partials = h2 @ Wfc1  (split-K=2, fp32)
      GemmArgs p = {};
      p.A = hbuf; p.lda = Dm;
      p.B = wfc1T + (size_t)i * FFm * Dm; p.ldb = Dm;
      p.C = pbuf; p.ldc = FFm;
      p.M = Sn; p.N = FFm; p.K = Dm; p.scale = 1.0f;
      gemm6<128, 128, 2, 3><<<dim3(32, 16, 2), 256, 0, stream>>>(p);
    }
    // ffn = gelu(p0+p1+bias)  (bf16)
    fc1red_kernel<<<dim3(Sn * FFm / 1024), 256, 0, stream>>>(pbuf, fc1_b + i * FFm, ffn);

    {  // fc2 partials = ffn @ Wfc2  (split-K=8, fp32)
      GemmArgs p = {};
      p.A = ffn; p.lda = FFm;
      p.B = wfc2T + (size_t)i * Dm * FFm; p.ldb = FFm;
      p.C = pbuf; p.ldc = Dm;
      p.M = Sn; p.N = Dm; p.K = FFm; p.scale = 1.0f;
      gemm6<128, 128, 8, 3><<<dim3(8, 16, 8), 256, 0, stream>>>(p);
    }
    if (i == 0) {
      // x = xbuf + fc2 + bias ; h = LN1[1](x)  (fused into next layer)
      redln_kernel<8><<<dim3(Sn), 256, 0, stream>>>(
          pbuf, fc2_b, xbuf, ln1_g + Dm, ln1_b + Dm, xbuf, hbuf);
    } else {
      fcred_kernel<8><<<dim3(Sn * Dm / 1024), 256, 0, stream>>>(
          pbuf, fc2_b + Dm, xbuf, (float*)d_out);
    }
  }
}

// Round 7
// 398.085 us; speedup vs baseline: 1.0816x; 1.0816x over previous
//
#include <hip/hip_runtime.h>
#include <hip/hip_bf16.h>
#include <math.h>

#define Dm 1024
#define Hn 16
#define HDm 64
#define FFm 4096
#define Sn 2048
#define SEG 512
#define EPSV 1e-6f

typedef __attribute__((ext_vector_type(4))) float f32x4;
typedef __attribute__((ext_vector_type(8))) short s16x8;
typedef __attribute__((ext_vector_type(4))) short s16x4;

__device__ inline short f2bf(float f) {
  __hip_bfloat16 h = __float2bfloat16(f);
  short s;
  __builtin_memcpy(&s, &h, 2);
  return s;
}
__device__ inline float bf2f(short s) {
  unsigned u = ((unsigned)(unsigned short)s) << 16;
  float f;
  __builtin_memcpy(&f, &u, 4);
  return f;
}

__device__ inline float wred_sum(float v) {
#pragma unroll
  for (int m = 32; m > 0; m >>= 1) v += __shfl_xor(v, m, 64);
  return v;
}
__device__ inline float wred_max(float v) {
#pragma unroll
  for (int m = 32; m > 0; m >>= 1) v = fmaxf(v, __shfl_xor(v, m, 64));
  return v;
}

// async global->LDS, 16B per lane. LDS dest is wave-uniform base + lane*16.
__device__ inline void gld16(const short* g, short* lds_base) {
  __builtin_amdgcn_global_load_lds(
      (const __attribute__((address_space(1))) void*)g,
      (__attribute__((address_space(3))) void*)lds_base, 16, 0, 0);
}

// ---------------- LayerNorm: fp32 in -> bf16 out ----------------
__global__ __launch_bounds__(256) void ln_kernel(const float* __restrict__ x,
                                                 const float* __restrict__ g,
                                                 const float* __restrict__ b,
                                                 short* __restrict__ out) {
  const int row = blockIdx.x;
  const int tid = threadIdx.x;
  f32x4 v = *reinterpret_cast<const f32x4*>(x + (size_t)row * Dm + tid * 4);
  float s1 = v.x + v.y + v.z + v.w;
  float s2 = v.x * v.x + v.y * v.y + v.z * v.z + v.w * v.w;
  s1 = wred_sum(s1);
  s2 = wred_sum(s2);
  __shared__ float t1[4], t2[4];
  if ((tid & 63) == 0) { t1[tid >> 6] = s1; t2[tid >> 6] = s2; }
  __syncthreads();
  s1 = t1[0] + t1[1] + t1[2] + t1[3];
  s2 = t2[0] + t2[1] + t2[2] + t2[3];
  const float mean = s1 * (1.0f / Dm);
  const float var = s2 * (1.0f / Dm) - mean * mean;
  const float rstd = rsqrtf(var + EPSV);
  f32x4 gv = *reinterpret_cast<const f32x4*>(g + tid * 4);
  f32x4 bv = *reinterpret_cast<const f32x4*>(b + tid * 4);
  s16x4 o;
#pragma unroll
  for (int j = 0; j < 4; ++j)
    o[j] = f2bf((v[j] - mean) * rstd * gv[j] + bv[j]);
  *reinterpret_cast<s16x4*>(out + (size_t)row * Dm + tid * 4) = o;
}

// ---- fused split-K reduce (fp32 partials) + residual + LayerNorm ----
template <int SPLIT>
__global__ __launch_bounds__(256) void redln_kernel(const float* __restrict__ pb,
                                                    const float* __restrict__ bias,
                                                    const float* __restrict__ res,
                                                    const float* __restrict__ g,
                                                    const float* __restrict__ b,
                                                    float* __restrict__ xout,
                                                    short* __restrict__ h) {
  const int row = blockIdx.x;
  const int tid = threadIdx.x;
  const size_t idx = (size_t)row * Dm + tid * 4;
  f32x4 o = *reinterpret_cast<const f32x4*>(res + idx);
  o += *reinterpret_cast<const f32x4*>(bias + tid * 4);
#pragma unroll
  for (int s = 0; s < SPLIT; ++s)
    o += *reinterpret_cast<const f32x4*>(pb + (size_t)s * Sn * Dm + idx);
  *reinterpret_cast<f32x4*>(xout + idx) = o;
  float s1 = o.x + o.y + o.z + o.w;
  float s2 = o.x * o.x + o.y * o.y + o.z * o.z + o.w * o.w;
  s1 = wred_sum(s1);
  s2 = wred_sum(s2);
  __shared__ float t1[4], t2[4];
  if ((tid & 63) == 0) { t1[tid >> 6] = s1; t2[tid >> 6] = s2; }
  __syncthreads();
  s1 = t1[0] + t1[1] + t1[2] + t1[3];
  s2 = t2[0] + t2[1] + t2[2] + t2[3];
  const float mean = s1 * (1.0f / Dm);
  const float var = s2 * (1.0f / Dm) - mean * mean;
  const float rstd = rsqrtf(var + EPSV);
  f32x4 gv = *reinterpret_cast<const f32x4*>(g + tid * 4);
  f32x4 bv = *reinterpret_cast<const f32x4*>(b + tid * 4);
  s16x4 ho;
#pragma unroll
  for (int j = 0; j < 4; ++j)
    ho[j] = f2bf((o[j] - mean) * rstd * gv[j] + bv[j]);
  *reinterpret_cast<s16x4*>(h + idx) = ho;
}

// ---- fused split-K reduce (bf16 partials) + residual + LayerNorm ----
template <int SPLIT>
__global__ __launch_bounds__(256) void redln_bf(const short* __restrict__ pb,
                                                const float* __restrict__ bias,
                                                const float* __restrict__ res,
                                                const float* __restrict__ g,
                                                const float* __restrict__ b,
                                                float* __restrict__ xout,
                                                short* __restrict__ h) {
  const int row = blockIdx.x;
  const int tid = threadIdx.x;
  const size_t idx = (size_t)row * Dm + tid * 4;
  f32x4 o = *reinterpret_cast<const f32x4*>(res + idx);
  o += *reinterpret_cast<const f32x4*>(bias + tid * 4);
#pragma unroll
  for (int s = 0; s < SPLIT; ++s) {
    s16x4 v = *reinterpret_cast<const s16x4*>(pb + (size_t)s * Sn * Dm + idx);
#pragma unroll
    for (int j = 0; j < 4; ++j) o[j] += bf2f(v[j]);
  }
  *reinterpret_cast<f32x4*>(xout + idx) = o;
  float s1 = o.x + o.y + o.z + o.w;
  float s2 = o.x * o.x + o.y * o.y + o.z * o.z + o.w * o.w;
  s1 = wred_sum(s1);
  s2 = wred_sum(s2);
  __shared__ float t1[4], t2[4];
  if ((tid & 63) == 0) { t1[tid >> 6] = s1; t2[tid >> 6] = s2; }
  __syncthreads();
  s1 = t1[0] + t1[1] + t1[2] + t1[3];
  s2 = t2[0] + t2[1] + t2[2] + t2[3];
  const float mean = s1 * (1.0f / Dm);
  const float var = s2 * (1.0f / Dm) - mean * mean;
  const float rstd = rsqrtf(var + EPSV);
  f32x4 gv = *reinterpret_cast<const f32x4*>(g + tid * 4);
  f32x4 bv = *reinterpret_cast<const f32x4*>(b + tid * 4);
  s16x4 ho;
#pragma unroll
  for (int j = 0; j < 4; ++j)
    ho[j] = f2bf((o[j] - mean) * rstd * gv[j] + bv[j]);
  *reinterpret_cast<s16x4*>(h + idx) = ho;
}

// ---- final split-K reduce (bf16 partials): out = sum + bias + res (fp32) ----
template <int SPLIT>
__global__ __launch_bounds__(256) void fcred_bf(const short* __restrict__ pb,
                                                const float* __restrict__ bias,
                                                const float* __restrict__ res,
                                                float* __restrict__ out) {
  const size_t i = ((size_t)blockIdx.x * 256 + threadIdx.x) * 4;
  f32x4 o = *reinterpret_cast<const f32x4*>(res + i);
  o += *reinterpret_cast<const f32x4*>(bias + (i & (Dm - 1)));
#pragma unroll
  for (int s = 0; s < SPLIT; ++s) {
    s16x4 v = *reinterpret_cast<const s16x4*>(pb + (size_t)s * Sn * Dm + i);
#pragma unroll
    for (int j = 0; j < 4; ++j) o[j] += bf2f(v[j]);
  }
  *reinterpret_cast<f32x4*>(out + i) = o;
}

// -------- softmax over 512-length rows; fp32 in -> compact bf16 probs --------
__global__ __launch_bounds__(128) void softmax_kernel(const float* __restrict__ scores,
                                                      short* __restrict__ probs) {
  const size_t rowoff = ((size_t)blockIdx.y * SEG + blockIdx.x) * SEG;
  const float* rp = scores + rowoff;
  const int tid = threadIdx.x;
  f32x4 v = *reinterpret_cast<const f32x4*>(rp + tid * 4);
  float mx = fmaxf(fmaxf(v.x, v.y), fmaxf(v.z, v.w));
  mx = wred_max(mx);
  __shared__ float rmax[2], rsum[2];
  if ((tid & 63) == 0) rmax[tid >> 6] = mx;
  __syncthreads();
  mx = fmaxf(rmax[0], rmax[1]);
  f32x4 e;
#pragma unroll
  for (int j = 0; j < 4; ++j) e[j] = __expf(v[j] - mx);
  float sm = e.x + e.y + e.z + e.w;
  sm = wred_sum(sm);
  if ((tid & 63) == 0) rsum[tid >> 6] = sm;
  __syncthreads();
  const float inv = 1.0f / (rsum[0] + rsum[1]);
  s16x4 o;
#pragma unroll
  for (int j = 0; j < 4; ++j) o[j] = f2bf(e[j] * inv);
  *reinterpret_cast<s16x4*>(probs + rowoff + tid * 4) = o;
}

// ---- transpose + convert: W (K x N fp32, row stride ldw) -> Wt (N x K bf16) ----
__global__ __launch_bounds__(256) void wt_kernel(const float* __restrict__ W,
                                                 short* __restrict__ Wt,
                                                 int K, int N, int ldw) {
  __shared__ float t[32][33];
  const int n0 = blockIdx.x * 32, k0 = blockIdx.y * 32;
  const int tx = threadIdx.x & 31, ty = threadIdx.x >> 5;
#pragma unroll
  for (int r = 0; r < 32; r += 8)
    t[r + ty][tx] = W[(size_t)(k0 + r + ty) * ldw + n0 + tx];
  __syncthreads();
#pragma unroll
  for (int r = 0; r < 32; r += 8)
    Wt[(size_t)(n0 + r + ty) * K + k0 + tx] = f2bf(t[tx][r + ty]);
}

// ---- bf16 transpose: V (K x N bf16, row stride ldv) -> Vt (N x K bf16) ----
__global__ __launch_bounds__(256) void wtb_kernel(const short* __restrict__ V,
                                                  short* __restrict__ Vt,
                                                  int K, int N, int ldv) {
  __shared__ short t[32][34];
  const int n0 = blockIdx.x * 32, k0 = blockIdx.y * 32;
  const int tx = threadIdx.x & 31, ty = threadIdx.x >> 5;
#pragma unroll
  for (int r = 0; r < 32; r += 8)
    t[r + ty][tx] = V[(size_t)(k0 + r + ty) * ldv + n0 + tx];
  __syncthreads();
#pragma unroll
  for (int r = 0; r < 32; r += 8)
    Vt[(size_t)(n0 + r + ty) * K + k0 + tx] = t[tx][r + ty];
}

struct GemmArgs {
  const short* A; int lda;
  const short* B; int ldb;
  void* C; int ldc;
  int M, N, K;
  const float* bias;
  const float* cosb; const float* sinb;
  float scale;
};

// ---------- gemm6: proven 2-barrier m97 path (QK^T / PV / proj-splitK) ----------
// MODE 1: QK^T batched (fp32*scale out). MODE 2: PV batched (bf16 out).
// MODE 3: dense split-K (fp32 partials, z = split index).
template <int BM, int BN, int SPLIT, int MODE>
__global__ __launch_bounds__(256) void gemm6(GemmArgs p) {
  constexpr int WN = 2;
  constexpr int WM = 2;
  constexpr int FI = BM / WM / 16;
  constexpr int FJ = BN / WN / 16;
  const int z = blockIdx.z;
  const short* A = p.A;
  const short* B = p.B;
  char* Cb = (char*)p.C;
  int kbase = 0, nkt = p.K >> 6;
  if (MODE == 1) {
    const int seg = z & 3, hh = z >> 2;
    A += (size_t)(seg * SEG) * p.lda + hh * HDm;
    B += (size_t)(seg * SEG) * p.ldb + hh * HDm;
    Cb += (size_t)z * SEG * SEG * 4;
  } else if (MODE == 2) {
    const int seg = z & 3, hh = z >> 2;
    A += (size_t)z * SEG * SEG;
    B += (size_t)(hh * HDm) * p.ldb + seg * SEG;
    Cb += ((size_t)seg * SEG * Dm + (size_t)hh * HDm) * 2;
  } else if (MODE == 3) {
    kbase = z * (p.K / SPLIT);
    nkt = (p.K / SPLIT) >> 6;
    Cb += (size_t)z * p.M * p.N * 4;
  }
  __shared__ short As[BM * 64];
  __shared__ short Bs[BN * 64];
  const int tid = threadIdx.x;
  const int lane = tid & 63;
  const int wave = tid >> 6;
  const int tileM = blockIdx.y * BM;
  const int tileN = blockIdx.x * BN;
  const int l15 = lane & 15;
  const int lg = lane >> 4;
  const int rx = l15 & 7;
  const int wr = (wave / WN) * (BM / WM);
  const int wc = (wave % WN) * (BN / WN);
  const int srow = lane >> 3;
  const int scol = ((lane & 7) ^ srow) * 8;

  f32x4 acc[FI][FJ] = {};

  const short* Ag = A + (size_t)(tileM + wave * 8 + srow) * p.lda + scol + kbase;
  const short* Bg = B + (size_t)(tileN + wave * 8 + srow) * p.ldb + scol + kbase;

  for (int kt = 0; kt < nkt; ++kt) {
    const int k0 = kt * 64;
#pragma unroll
    for (int j = 0; j < BM / 32; ++j)
      gld16(Ag + (size_t)(j * 32) * p.lda + k0, &As[(j * 32 + wave * 8) * 64]);
#pragma unroll
    for (int j = 0; j < BN / 32; ++j)
      gld16(Bg + (size_t)(j * 32) * p.ldb + k0, &Bs[(j * 32 + wave * 8) * 64]);
    __syncthreads();
#pragma unroll
    for (int kk = 0; kk < 64; kk += 32) {
      const int kkc = kk >> 3;
      s16x8 af[FI], bfr[FJ];
#pragma unroll
      for (int f = 0; f < FI; ++f)
        af[f] = *reinterpret_cast<const s16x8*>(
            &As[(wr + f * 16 + l15) * 64 + (((lg + kkc) ^ rx) << 3)]);
#pragma unroll
      for (int f = 0; f < FJ; ++f)
        bfr[f] = *reinterpret_cast<const s16x8*>(
            &Bs[(wc + f * 16 + l15) * 64 + (((lg + kkc) ^ rx) << 3)]);
#pragma unroll
      for (int fi = 0; fi < FI; ++fi)
#pragma unroll
        for (int fj = 0; fj < FJ; ++fj)
          acc[fi][fj] = __builtin_amdgcn_mfma_f32_16x16x32_bf16(
              af[fi], bfr[fj], acc[fi][fj], 0, 0, 0);
    }
    __syncthreads();
  }

#pragma unroll
  for (int fi = 0; fi < FI; ++fi) {
#pragma unroll
    for (int fj = 0; fj < FJ; ++fj) {
#pragma unroll
      for (int r = 0; r < 4; ++r) {
        const int row = tileM + wr + fi * 16 + lg * 4 + r;
        const int col = tileN + wc + fj * 16 + l15;
        const float v = acc[fi][fj][r] * p.scale;
        if (MODE == 2)
          reinterpret_cast<short*>(Cb)[(size_t)row * p.ldc + col] = f2bf(v);
        else
          reinterpret_cast<float*>(Cb)[(size_t)row * p.ldc + col] = v;
      }
    }
  }
}

// ---------- gemm8: deep-pipelined 4-phase/K-tile template ----------
// BM=128 x BN=256, 512 threads (8 waves: 2M x 4N, 64x64 out each), BK=64,
// 96 KB double-buffered LDS. Per phase: {ds_read subtile | stage one unit ->
// s_barrier -> lgkmcnt(0) -> setprio(1) -> 8 MFMA -> setprio(0)}.
// One vmcnt(0) per K-tile at ph3, waiting loads issued ~3 phases earlier.
// EPI: 0 = QKV bias+RoPE (bf16), 1 = FC1 bias+GELU (bf16),
//      2 = split-K bf16 partials (no bias).
template <int EPI, int SPLIT>
__global__ __launch_bounds__(512, 2) void gemm8(GemmArgs p) {
  __shared__ short As[2][128 * 64];
  __shared__ short Bs[2][256 * 64];
  const int tid = threadIdx.x;
  const int lane = tid & 63;
  const int wave = tid >> 6;
  const int wm = wave >> 2, wn = wave & 3;
  const int l15 = lane & 15, lg = lane >> 4, rx = l15 & 7;
  const int wr = wm * 64, wc = wn * 64;

  // XCD-aware chunked swizzle (grids here are multiples of 8)
  const int gx = gridDim.x;
  const int nwg = gx * gridDim.y;
  const int orig = blockIdx.y * gx + blockIdx.x;
  const int sid = (orig & 7) * (nwg >> 3) + (orig >> 3);
  const int tileM = (sid / gx) * 128;
  const int tileN = (sid % gx) * 256;

  const int z = blockIdx.z;
  int kbase = 0, nkt = p.K >> 6;
  if (SPLIT > 1) {
    kbase = z * (p.K / SPLIT);
    nkt = (p.K / SPLIT) >> 6;
  }

  // staging: 512 threads; thread t covers row (j*64 + t>>3), chunk t&7.
  const int srow = tid >> 3;                        // 0..63
  const int schunk = ((tid & 7) ^ (srow & 7)) * 8;  // pre-swizzled source
  const short* Ag = p.A + (size_t)(tileM + srow) * p.lda + schunk + kbase;
  const short* Bg = p.B + (size_t)(tileN + srow) * p.ldb + schunk + kbase;

  auto stageA = [&](int bb, int kt) {
    const int k0 = kt * 64;
    gld16(Ag + k0, &As[bb][wave * 512]);
    gld16(Ag + (size_t)64 * p.lda + k0, &As[bb][4096 + wave * 512]);
  };
  auto stageB0 = [&](int bb, int kt) {
    const int k0 = kt * 64;
    gld16(Bg + k0, &Bs[bb][wave * 512]);
    gld16(Bg + (size_t)64 * p.ldb + k0, &Bs[bb][4096 + wave * 512]);
  };
  auto stageB1 = [&](int bb, int kt) {
    const int k0 = kt * 64;
    gld16(Bg + (size_t)128 * p.ldb + k0, &Bs[bb][8192 + wave * 512]);
    gld16(Bg + (size_t)192 * p.ldb + k0, &Bs[bb][12288 + wave * 512]);
  };
  auto rdA = [&](int bb, int fi, int kkc) -> s16x8 {
    return *reinterpret_cast<const s16x8*>(
        &As[bb][(wr + fi * 16 + l15) * 64 + (((lg + kkc) ^ rx) << 3)]);
  };
  auto rdB = [&](int bb, int fj, int kkc) -> s16x8 {
    return *reinterpret_cast<const s16x8*>(
        &Bs[bb][(wc + fj * 16 + l15) * 64 + (((lg + kkc) ^ rx) << 3)]);
  };

  f32x4 acc[4][4] = {};

  stageA(0, 0); stageB0(0, 0); stageB1(0, 0);
  asm volatile("s_waitcnt vmcnt(0)" ::: "memory");
  __builtin_amdgcn_s_barrier();
  __builtin_amdgcn_sched_barrier(0);

  for (int t = 0; t < nkt; ++t) {
    const int bb = t & 1, nb = bb ^ 1;
    const bool pf = (t + 1 < nkt);
    s16x8 bk[4], aa[2];
    // ---- ph0: kk=0, fi=0..1 ----
#pragma unroll
    for (int fj = 0; fj < 4; ++fj) bk[fj] = rdB(bb, fj, 0);
    aa[0] = rdA(bb, 0, 0); aa[1] = rdA(bb, 1, 0);
    if (pf) { stageA(nb, t + 1); stageB0(nb, t + 1); }
    __builtin_amdgcn_s_barrier();
    asm volatile("s_waitcnt lgkmcnt(0)" ::: "memory");
    __builtin_amdgcn_sched_barrier(0);
    __builtin_amdgcn_s_setprio(1);
#pragma unroll
    for (int fi = 0; fi < 2; ++fi)
#pragma unroll
      for (int fj = 0; fj < 4; ++fj)
        acc[fi][fj] = __builtin_amdgcn_mfma_f32_16x16x32_bf16(
            aa[fi], bk[fj], acc[fi][fj], 0, 0, 0);
    __builtin_amdgcn_s_setprio(0);
    // ---- ph1: kk=0, fi=2..3 ----
    aa[0] = rdA(bb, 2, 0); aa[1] = rdA(bb, 3, 0);
    if (pf) stageB1(nb, t + 1);
    __builtin_amdgcn_s_barrier();
    asm volatile("s_waitcnt lgkmcnt(0)" ::: "memory");
    __builtin_amdgcn_sched_barrier(0);
    __builtin_amdgcn_s_setprio(1);
#pragma unroll
    for (int fi = 0; fi < 2; ++fi)
#pragma unroll
      for (int fj = 0; fj < 4; ++fj)
        acc[2 + fi][fj] = __builtin_amdgcn_mfma_f32_16x16x32_bf16(
            aa[fi], bk[fj], acc[2 + fi][fj], 0, 0, 0);
    __builtin_amdgcn_s_setprio(0);
    // ---- ph2: kk=32, fi=0..1 ----
#pragma unroll
    for (int fj = 0; fj < 4; ++fj) bk[fj] = rdB(bb, fj, 4);
    aa[0] = rdA(bb, 0, 4); aa[1] = rdA(bb, 1, 4);
    __builtin_amdgcn_s_barrier();
    asm volatile("s_waitcnt lgkmcnt(0)" ::: "memory");
    __builtin_amdgcn_sched_barrier(0);
    __builtin_amdgcn_s_setprio(1);
#pragma unroll
    for (int fi = 0; fi < 2; ++fi)
#pragma unroll
      for (int fj = 0; fj < 4; ++fj)
        acc[fi][fj] = __builtin_amdgcn_mfma_f32_16x16x32_bf16(
            aa[fi], bk[fj], acc[fi][fj], 0, 0, 0);
    __builtin_amdgcn_s_setprio(0);
    // ---- ph3: kk=32, fi=2..3 ; vmcnt fence for next tile's buffer ----
    aa[0] = rdA(bb, 2, 4); aa[1] = rdA(bb, 3, 4);
    asm volatile("s_waitcnt vmcnt(0)" ::: "memory");
    __builtin_amdgcn_s_barrier();
    asm volatile("s_waitcnt lgkmcnt(0)" ::: "memory");
    __builtin_amdgcn_sched_barrier(0);
    __builtin_amdgcn_s_setprio(1);
#pragma unroll
    for (int fi = 0; fi < 2; ++fi)
#pragma unroll
      for (int fj = 0; fj < 4; ++fj)
        acc[2 + fi][fj] = __builtin_amdgcn_mfma_f32_16x16x32_bf16(
            aa[fi], bk[fj], acc[2 + fi][fj], 0, 0, 0);
    __builtin_amdgcn_s_setprio(0);
  }

  // -------- epilogue --------
  if (EPI == 0) {
    short* Cs = (short*)p.C;
    const bool isqk = (tileN + wc) < 2048;
#pragma unroll
    for (int fi = 0; fi < 4; ++fi) {
#pragma unroll
      for (int fj = 0; fj < 4; ++fj) {
#pragma unroll
        for (int r = 0; r < 4; ++r) {
          const int row = tileM + wr + fi * 16 + lg * 4 + r;
          const int col = tileN + wc + fj * 16 + l15;
          float a0 = acc[fi][fj][r] + p.bias[col];
          float vout;
          if (isqk) {
            float a1 = acc[fi][fj ^ 2][r] + p.bias[col ^ 32];
            const int dl = fj * 16 + l15;
            const float c = p.cosb[(size_t)row * HDm + dl];
            const float sn = p.sinb[(size_t)row * HDm + dl];
            vout = (fj < 2) ? (a0 * c - a1 * sn) : (a0 * c + a1 * sn);
          } else {
            vout = a0;
          }
          Cs[(size_t)row * p.ldc + col] = f2bf(vout);
        }
      }
    }
  } else if (EPI == 1) {
    short* Cs = (short*)p.C;
#pragma unroll
    for (int fi = 0; fi < 4; ++fi) {
#pragma unroll
      for (int fj = 0; fj < 4; ++fj) {
#pragma unroll
        for (int r = 0; r < 4; ++r) {
          const int row = tileM + wr + fi * 16 + lg * 4 + r;
          const int col = tileN + wc + fj * 16 + l15;
          float v = acc[fi][fj][r] + p.bias[col];
          v = 0.5f * v * (1.0f + erff(v * 0.70710678118654752f));
          Cs[(size_t)row * p.ldc + col] = f2bf(v);
        }
      }
    }
  } else {
    short* Cs = (short*)p.C + (size_t)z * p.M * p.N;
#pragma unroll
    for (int fi = 0; fi < 4; ++fi) {
#pragma unroll
      for (int fj = 0; fj < 4; ++fj) {
#pragma unroll
        for (int r = 0; r < 4; ++r) {
          const int row = tileM + wr + fi * 16 + lg * 4 + r;
          const int col = tileN + wc + fj * 16 + l15;
          Cs[(size_t)row * p.ldc + col] = f2bf(acc[fi][fj][r]);
        }
      }
    }
  }
}

extern "C" void kernel_launch(void* const* d_in, const int* in_sizes, int n_in,
                              void* d_out, int out_size, void* d_ws, size_t ws_size,
                              hipStream_t stream) {
  const float* x0 = (const float*)d_in[0];
  const float* cosb = (const float*)d_in[2];
  const float* sinb = (const float*)d_in[3];
  const float* ln1_g = (const float*)d_in[4];
  const float* ln1_b = (const float*)d_in[5];
  const float* qkv_w = (const float*)d_in[6];
  const float* qkv_b = (const float*)d_in[7];
  const float* proj_w = (const float*)d_in[8];
  const float* proj_b = (const float*)d_in[9];
  const float* ln2_g = (const float*)d_in[10];
  const float* ln2_b = (const float*)d_in[11];
  const float* fc1_w = (const float*)d_in[12];
  const float* fc1_b = (const float*)d_in[13];
  const float* fc2_w = (const float*)d_in[14];
  const float* fc2_b = (const float*)d_in[15];

  char* ws = (char*)d_ws;
  size_t off = 0;
  auto alloc = [&](size_t bytes) {
    void* p = ws + off;
    off += (bytes + 255) & ~(size_t)255;
    return p;
  };
  short* wqkvT = (short*)alloc((size_t)2 * 3072 * 1024 * 2);
  short* wprojT = (short*)alloc((size_t)2 * 1024 * 1024 * 2);
  short* wfc1T = (short*)alloc((size_t)2 * 4096 * 1024 * 2);
  short* wfc2T = (short*)alloc((size_t)2 * 1024 * 4096 * 2);
  float* xbuf = (float*)alloc((size_t)Sn * Dm * 4);
  short* hbuf = (short*)alloc((size_t)Sn * Dm * 2);
  short* qkvb = (short*)alloc((size_t)Sn * 3 * Dm * 2);
  short* probs = (short*)alloc((size_t)64 * SEG * SEG * 2);
  // scores fp32 (67MB); also split-K partial space (disjoint lifetimes):
  // proj fp32 2x8.4MB, fc2 bf16 4x4.2MB.
  float* scores = (float*)alloc((size_t)64 * SEG * SEG * 4);
  float* pbuf = scores;
  short* pbufS = (short*)scores;
  short* ao = (short*)alloc((size_t)Sn * Dm * 2);
  short* ffn = (short*)alloc((size_t)Sn * FFm * 2);
  short* vT = ffn;  // vT (4.2MB) aliases ffn: dead during attention phase
  (void)ws_size; (void)in_sizes; (void)n_in; (void)out_size;

  for (int i = 0; i < 2; ++i) {
    wt_kernel<<<dim3(96, 32), 256, 0, stream>>>(
        qkv_w + (size_t)i * Dm * 3072, wqkvT + (size_t)i * 3072 * Dm, Dm, 3072, 3072);
    wt_kernel<<<dim3(32, 32), 256, 0, stream>>>(
        proj_w + (size_t)i * Dm * Dm, wprojT + (size_t)i * Dm * Dm, Dm, Dm, Dm);
    wt_kernel<<<dim3(128, 32), 256, 0, stream>>>(
        fc1_w + (size_t)i * Dm * FFm, wfc1T + (size_t)i * FFm * Dm, Dm, FFm, FFm);
    wt_kernel<<<dim3(32, 128), 256, 0, stream>>>(
        fc2_w + (size_t)i * FFm * Dm, wfc2T + (size_t)i * Dm * FFm, FFm, Dm, Dm);
  }

  // layer 0 LN1 (layer-boundary LNs are fused into the reduces)
  ln_kernel<<<dim3(Sn), 256, 0, stream>>>(x0, ln1_g, ln1_b, hbuf);

  for (int i = 0; i < 2; ++i) {
    const float* xin = i ? (const float*)xbuf : x0;

    {  // qkvb = rope(h @ Wqkv + b)  (deep template, bf16 out)
      GemmArgs p = {};
      p.A = hbuf; p.lda = Dm;
      p.B = wqkvT + (size_t)i * 3072 * Dm; p.ldb = Dm;
      p.C = qkvb; p.ldc = 3 * Dm;
      p.M = Sn; p.N = 3 * Dm; p.K = Dm;
      p.bias = qkv_b + i * 3 * Dm; p.cosb = cosb; p.sinb = sinb;
      gemm8<0, 1><<<dim3(12, 16, 1), 512, 0, stream>>>(p);
    }

    // v (bf16 cols 2048.. of qkvb) -> vT
    wtb_kernel<<<dim3(32, 64), 256, 0, stream>>>(qkvb + 2 * Dm, vT, Sn, Dm, 3 * Dm);

    {  // scores = scale * q @ k^T  per (head, seg)  (fp32 out)
      GemmArgs p = {};
      p.A = qkvb; p.lda = 3 * Dm;
      p.B = qkvb + Dm; p.ldb = 3 * Dm;
      p.C = scores; p.ldc = SEG;
      p.M = SEG; p.N = SEG; p.K = HDm; p.scale = 0.125f;
      gemm6<128, 128, 1, 1><<<dim3(4, 4, 64), 256, 0, stream>>>(p);
    }

    softmax_kernel<<<dim3(SEG, 64), 128, 0, stream>>>(scores, probs);

    {  // ao = probs @ V  per (head, seg)  (bf16 out)
      GemmArgs p = {};
      p.A = probs; p.lda = SEG;
      p.B = vT; p.ldb = Sn;
      p.C = ao; p.ldc = Dm;
      p.M = SEG; p.N = HDm; p.K = SEG; p.scale = 1.0f;
      gemm6<64, 64, 1, 2><<<dim3(1, 8, 64), 256, 0, stream>>>(p);
    }

    {  // proj partials = ao @ Wproj  (split-K=2, fp32)
      GemmArgs p = {};
      p.A = ao; p.lda = Dm;
      p.B = wprojT + (size_t)i * Dm * Dm; p.ldb = Dm;
      p.C = pbuf; p.ldc = Dm;
      p.M = Sn; p.N = Dm; p.K = Dm; p.scale = 1.0f;
      gemm6<64, 64, 2, 3><<<dim3(16, 32, 2), 256, 0, stream>>>(p);
    }
    // x = xin + proj + bias ; h = LN2(x)
    redln_kernel<2><<<dim3(Sn), 256, 0, stream>>>(
        pbuf, proj_b + i * Dm, xin, ln2_g + i * Dm, ln2_b + i * Dm, xbuf, hbuf);

    {  // ffn = gelu(h2 @ Wfc1 + b)  (deep template, bf16 out, no partials)
      GemmArgs p = {};
      p.A = hbuf; p.lda = Dm;
      p.B = wfc1T + (size_t)i * FFm * Dm; p.ldb = Dm;
      p.C = ffn; p.ldc = FFm;
      p.M = Sn; p.N = FFm; p.K = Dm;
      p.bias = fc1_b + i * FFm;
      gemm8<1, 1><<<dim3(16, 16, 1), 512, 0, stream>>>(p);
    }

    {  // fc2 partials = ffn @ Wfc2  (deep template, split-K=4, bf16 partials)
      GemmArgs p = {};
      p.A = ffn; p.lda = FFm;
      p.B = wfc2T + (size_t)i * Dm * FFm; p.ldb = FFm;
      p.C = pbufS; p.ldc = Dm;
      p.M = Sn; p.N = Dm; p.K = FFm;
      gemm8<2, 4><<<dim3(4, 16, 4), 512, 0, stream>>>(p);
    }
    if (i == 0) {
      // x = xbuf + fc2 + bias ; h = LN1[1](x)
      redln_bf<4><<<dim3(Sn), 256, 0, stream>>>(
          pbufS, fc2_b, xbuf, ln1_g + Dm, ln1_b + Dm, xbuf, hbuf);
    } else {
      fcred_bf<4><<<dim3(Sn * Dm / 1024), 256, 0, stream>>>(
          pbufS, fc2_b + Dm, xbuf, (float*)d_out);
    }
  }
}

// Round 8
// 358.753 us; speedup vs baseline: 1.2001x; 1.1096x over previous
//
#include <hip/hip_runtime.h>
#include <hip/hip_bf16.h>
#include <math.h>

#define Dm 1024
#define Hn 16
#define HDm 64
#define FFm 4096
#define Sn 2048
#define SEG 512
#define EPSV 1e-6f

typedef __attribute__((ext_vector_type(4))) float f32x4;
typedef __attribute__((ext_vector_type(8))) short s16x8;
typedef __attribute__((ext_vector_type(4))) short s16x4;

__device__ inline short f2bf(float f) {
  __hip_bfloat16 h = __float2bfloat16(f);
  short s;
  __builtin_memcpy(&s, &h, 2);
  return s;
}
__device__ inline float bf2f(short s) {
  unsigned u = ((unsigned)(unsigned short)s) << 16;
  float f;
  __builtin_memcpy(&f, &u, 4);
  return f;
}

__device__ inline float wred_sum(float v) {
#pragma unroll
  for (int m = 32; m > 0; m >>= 1) v += __shfl_xor(v, m, 64);
  return v;
}
__device__ inline float wred_max(float v) {
#pragma unroll
  for (int m = 32; m > 0; m >>= 1) v = fmaxf(v, __shfl_xor(v, m, 64));
  return v;
}

// async global->LDS, 16B per lane. LDS dest is wave-uniform base + lane*16.
__device__ inline void gld16(const short* g, short* lds_base) {
  __builtin_amdgcn_global_load_lds(
      (const __attribute__((address_space(1))) void*)g,
      (__attribute__((address_space(3))) void*)lds_base, 16, 0, 0);
}

// ---------------- LayerNorm: fp32 in -> bf16 out ----------------
__global__ __launch_bounds__(256) void ln_kernel(const float* __restrict__ x,
                                                 const float* __restrict__ g,
                                                 const float* __restrict__ b,
                                                 short* __restrict__ out) {
  const int row = blockIdx.x;
  const int tid = threadIdx.x;
  f32x4 v = *reinterpret_cast<const f32x4*>(x + (size_t)row * Dm + tid * 4);
  float s1 = v.x + v.y + v.z + v.w;
  float s2 = v.x * v.x + v.y * v.y + v.z * v.z + v.w * v.w;
  s1 = wred_sum(s1);
  s2 = wred_sum(s2);
  __shared__ float t1[4], t2[4];
  if ((tid & 63) == 0) { t1[tid >> 6] = s1; t2[tid >> 6] = s2; }
  __syncthreads();
  s1 = t1[0] + t1[1] + t1[2] + t1[3];
  s2 = t2[0] + t2[1] + t2[2] + t2[3];
  const float mean = s1 * (1.0f / Dm);
  const float var = s2 * (1.0f / Dm) - mean * mean;
  const float rstd = rsqrtf(var + EPSV);
  f32x4 gv = *reinterpret_cast<const f32x4*>(g + tid * 4);
  f32x4 bv = *reinterpret_cast<const f32x4*>(b + tid * 4);
  s16x4 o;
#pragma unroll
  for (int j = 0; j < 4; ++j)
    o[j] = f2bf((v[j] - mean) * rstd * gv[j] + bv[j]);
  *reinterpret_cast<s16x4*>(out + (size_t)row * Dm + tid * 4) = o;
}

// ---- fused split-K reduce (fp32 partials) + residual + LayerNorm ----
template <int SPLIT>
__global__ __launch_bounds__(256) void redln_kernel(const float* __restrict__ pb,
                                                    const float* __restrict__ bias,
                                                    const float* __restrict__ res,
                                                    const float* __restrict__ g,
                                                    const float* __restrict__ b,
                                                    float* __restrict__ xout,
                                                    short* __restrict__ h) {
  const int row = blockIdx.x;
  const int tid = threadIdx.x;
  const size_t idx = (size_t)row * Dm + tid * 4;
  f32x4 o = *reinterpret_cast<const f32x4*>(res + idx);
  o += *reinterpret_cast<const f32x4*>(bias + tid * 4);
#pragma unroll
  for (int s = 0; s < SPLIT; ++s)
    o += *reinterpret_cast<const f32x4*>(pb + (size_t)s * Sn * Dm + idx);
  *reinterpret_cast<f32x4*>(xout + idx) = o;
  float s1 = o.x + o.y + o.z + o.w;
  float s2 = o.x * o.x + o.y * o.y + o.z * o.z + o.w * o.w;
  s1 = wred_sum(s1);
  s2 = wred_sum(s2);
  __shared__ float t1[4], t2[4];
  if ((tid & 63) == 0) { t1[tid >> 6] = s1; t2[tid >> 6] = s2; }
  __syncthreads();
  s1 = t1[0] + t1[1] + t1[2] + t1[3];
  s2 = t2[0] + t2[1] + t2[2] + t2[3];
  const float mean = s1 * (1.0f / Dm);
  const float var = s2 * (1.0f / Dm) - mean * mean;
  const float rstd = rsqrtf(var + EPSV);
  f32x4 gv = *reinterpret_cast<const f32x4*>(g + tid * 4);
  f32x4 bv = *reinterpret_cast<const f32x4*>(b + tid * 4);
  s16x4 ho;
#pragma unroll
  for (int j = 0; j < 4; ++j)
    ho[j] = f2bf((o[j] - mean) * rstd * gv[j] + bv[j]);
  *reinterpret_cast<s16x4*>(h + idx) = ho;
}

// ---- fused split-K reduce (bf16 partials) + residual + LayerNorm ----
template <int SPLIT>
__global__ __launch_bounds__(256) void redln_bf(const short* __restrict__ pb,
                                                const float* __restrict__ bias,
                                                const float* __restrict__ res,
                                                const float* __restrict__ g,
                                                const float* __restrict__ b,
                                                float* __restrict__ xout,
                                                short* __restrict__ h) {
  const int row = blockIdx.x;
  const int tid = threadIdx.x;
  const size_t idx = (size_t)row * Dm + tid * 4;
  f32x4 o = *reinterpret_cast<const f32x4*>(res + idx);
  o += *reinterpret_cast<const f32x4*>(bias + tid * 4);
#pragma unroll
  for (int s = 0; s < SPLIT; ++s) {
    s16x4 v = *reinterpret_cast<const s16x4*>(pb + (size_t)s * Sn * Dm + idx);
#pragma unroll
    for (int j = 0; j < 4; ++j) o[j] += bf2f(v[j]);
  }
  *reinterpret_cast<f32x4*>(xout + idx) = o;
  float s1 = o.x + o.y + o.z + o.w;
  float s2 = o.x * o.x + o.y * o.y + o.z * o.z + o.w * o.w;
  s1 = wred_sum(s1);
  s2 = wred_sum(s2);
  __shared__ float t1[4], t2[4];
  if ((tid & 63) == 0) { t1[tid >> 6] = s1; t2[tid >> 6] = s2; }
  __syncthreads();
  s1 = t1[0] + t1[1] + t1[2] + t1[3];
  s2 = t2[0] + t2[1] + t2[2] + t2[3];
  const float mean = s1 * (1.0f / Dm);
  const float var = s2 * (1.0f / Dm) - mean * mean;
  const float rstd = rsqrtf(var + EPSV);
  f32x4 gv = *reinterpret_cast<const f32x4*>(g + tid * 4);
  f32x4 bv = *reinterpret_cast<const f32x4*>(b + tid * 4);
  s16x4 ho;
#pragma unroll
  for (int j = 0; j < 4; ++j)
    ho[j] = f2bf((o[j] - mean) * rstd * gv[j] + bv[j]);
  *reinterpret_cast<s16x4*>(h + idx) = ho;
}

// ---- final split-K reduce (bf16 partials): out = sum + bias + res (fp32) ----
template <int SPLIT>
__global__ __launch_bounds__(256) void fcred_bf(const short* __restrict__ pb,
                                                const float* __restrict__ bias,
                                                const float* __restrict__ res,
                                                float* __restrict__ out) {
  const size_t i = ((size_t)blockIdx.x * 256 + threadIdx.x) * 4;
  f32x4 o = *reinterpret_cast<const f32x4*>(res + i);
  o += *reinterpret_cast<const f32x4*>(bias + (i & (Dm - 1)));
#pragma unroll
  for (int s = 0; s < SPLIT; ++s) {
    s16x4 v = *reinterpret_cast<const s16x4*>(pb + (size_t)s * Sn * Dm + i);
#pragma unroll
    for (int j = 0; j < 4; ++j) o[j] += bf2f(v[j]);
  }
  *reinterpret_cast<f32x4*>(out + i) = o;
}

// -------- softmax over 512-length rows; fp32 in -> compact bf16 probs --------
__global__ __launch_bounds__(128) void softmax_kernel(const float* __restrict__ scores,
                                                      short* __restrict__ probs) {
  const size_t rowoff = ((size_t)blockIdx.y * SEG + blockIdx.x) * SEG;
  const float* rp = scores + rowoff;
  const int tid = threadIdx.x;
  f32x4 v = *reinterpret_cast<const f32x4*>(rp + tid * 4);
  float mx = fmaxf(fmaxf(v.x, v.y), fmaxf(v.z, v.w));
  mx = wred_max(mx);
  __shared__ float rmax[2], rsum[2];
  if ((tid & 63) == 0) rmax[tid >> 6] = mx;
  __syncthreads();
  mx = fmaxf(rmax[0], rmax[1]);
  f32x4 e;
#pragma unroll
  for (int j = 0; j < 4; ++j) e[j] = __expf(v[j] - mx);
  float sm = e.x + e.y + e.z + e.w;
  sm = wred_sum(sm);
  if ((tid & 63) == 0) rsum[tid >> 6] = sm;
  __syncthreads();
  const float inv = 1.0f / (rsum[0] + rsum[1]);
  s16x4 o;
#pragma unroll
  for (int j = 0; j < 4; ++j) o[j] = f2bf(e[j] * inv);
  *reinterpret_cast<s16x4*>(probs + rowoff + tid * 4) = o;
}

// ---- transpose + convert: W (K x N fp32, row stride ldw) -> Wt (N x K bf16) ----
__global__ __launch_bounds__(256) void wt_kernel(const float* __restrict__ W,
                                                 short* __restrict__ Wt,
                                                 int K, int N, int ldw) {
  __shared__ float t[32][33];
  const int n0 = blockIdx.x * 32, k0 = blockIdx.y * 32;
  const int tx = threadIdx.x & 31, ty = threadIdx.x >> 5;
#pragma unroll
  for (int r = 0; r < 32; r += 8)
    t[r + ty][tx] = W[(size_t)(k0 + r + ty) * ldw + n0 + tx];
  __syncthreads();
#pragma unroll
  for (int r = 0; r < 32; r += 8)
    Wt[(size_t)(n0 + r + ty) * K + k0 + tx] = f2bf(t[tx][r + ty]);
}

// ---- bf16 transpose: V (K x N bf16, row stride ldv) -> Vt (N x K bf16) ----
__global__ __launch_bounds__(256) void wtb_kernel(const short* __restrict__ V,
                                                  short* __restrict__ Vt,
                                                  int K, int N, int ldv) {
  __shared__ short t[32][34];
  const int n0 = blockIdx.x * 32, k0 = blockIdx.y * 32;
  const int tx = threadIdx.x & 31, ty = threadIdx.x >> 5;
#pragma unroll
  for (int r = 0; r < 32; r += 8)
    t[r + ty][tx] = V[(size_t)(k0 + r + ty) * ldv + n0 + tx];
  __syncthreads();
#pragma unroll
  for (int r = 0; r < 32; r += 8)
    Vt[(size_t)(n0 + r + ty) * K + k0 + tx] = t[tx][r + ty];
}

struct GemmArgs {
  const short* A; int lda;
  const short* B; int ldb;
  void* C; int ldc;
  int M, N, K;
  const float* bias;
  const float* cosb; const float* sinb;
  float scale;
};

// ---------- gemm6: 2-barrier m97 path, conflict-free, XCD-swizzled ----------
// MODE 1: QK^T batched (fp32*scale out). MODE 2: PV batched (bf16 out).
// MODE 3: dense split-K (fp32 partials). MODE 4: dense + bias + RoPE (bf16).
// MODE 5: dense + bias + GELU (bf16). MODE 6: dense split-K (bf16 partials).
template <int BM, int BN, int SPLIT, int MODE>
__global__ __launch_bounds__(256) void gemm6(GemmArgs p) {
  constexpr int WN = 2;
  constexpr int WM = 2;
  constexpr int FI = BM / WM / 16;
  constexpr int FJ = BN / WN / 16;
  const int z = blockIdx.z;
  const short* A = p.A;
  const short* B = p.B;
  char* Cb = (char*)p.C;
  int kbase = 0, nkt = p.K >> 6;
  int tileM, tileN;
  if (MODE == 1 || MODE == 2) {
    tileM = blockIdx.y * BM;
    tileN = blockIdx.x * BN;
  } else {
    // XCD-aware chunked swizzle; dense grids are multiples of 8.
    const int gx = gridDim.x;
    const int nwg = gx * gridDim.y;
    const int orig = blockIdx.y * gx + blockIdx.x;
    const int sid = (orig & 7) * (nwg >> 3) + (orig >> 3);
    tileM = (sid / gx) * BM;
    tileN = (sid % gx) * BN;
  }
  if (MODE == 1) {
    const int seg = z & 3, hh = z >> 2;
    A += (size_t)(seg * SEG) * p.lda + hh * HDm;
    B += (size_t)(seg * SEG) * p.ldb + hh * HDm;
    Cb += (size_t)z * SEG * SEG * 4;
  } else if (MODE == 2) {
    const int seg = z & 3, hh = z >> 2;
    A += (size_t)z * SEG * SEG;
    B += (size_t)(hh * HDm) * p.ldb + seg * SEG;
    Cb += ((size_t)seg * SEG * Dm + (size_t)hh * HDm) * 2;
  } else if (MODE == 3 || MODE == 6) {
    kbase = z * (p.K / SPLIT);
    nkt = (p.K / SPLIT) >> 6;
    Cb += (size_t)z * p.M * p.N * ((MODE == 3) ? 4 : 2);
  }
  __shared__ short As[BM * 64];
  __shared__ short Bs[BN * 64];
  const int tid = threadIdx.x;
  const int lane = tid & 63;
  const int wave = tid >> 6;
  const int l15 = lane & 15;
  const int lg = lane >> 4;
  const int rx = l15 & 7;
  const int wr = (wave / WN) * (BM / WM);
  const int wc = (wave % WN) * (BN / WN);
  const int srow = lane >> 3;
  const int scol = ((lane & 7) ^ srow) * 8;

  f32x4 acc[FI][FJ] = {};

  const short* Ag = A + (size_t)(tileM + wave * 8 + srow) * p.lda + scol + kbase;
  const short* Bg = B + (size_t)(tileN + wave * 8 + srow) * p.ldb + scol + kbase;

  for (int kt = 0; kt < nkt; ++kt) {
    const int k0 = kt * 64;
#pragma unroll
    for (int j = 0; j < BM / 32; ++j)
      gld16(Ag + (size_t)(j * 32) * p.lda + k0, &As[(j * 32 + wave * 8) * 64]);
#pragma unroll
    for (int j = 0; j < BN / 32; ++j)
      gld16(Bg + (size_t)(j * 32) * p.ldb + k0, &Bs[(j * 32 + wave * 8) * 64]);
    __syncthreads();
#pragma unroll
    for (int kk = 0; kk < 64; kk += 32) {
      const int kkc = kk >> 3;
      s16x8 af[FI], bfr[FJ];
#pragma unroll
      for (int f = 0; f < FI; ++f)
        af[f] = *reinterpret_cast<const s16x8*>(
            &As[(wr + f * 16 + l15) * 64 + (((lg + kkc) ^ rx) << 3)]);
#pragma unroll
      for (int f = 0; f < FJ; ++f)
        bfr[f] = *reinterpret_cast<const s16x8*>(
            &Bs[(wc + f * 16 + l15) * 64 + (((lg + kkc) ^ rx) << 3)]);
#pragma unroll
      for (int fi = 0; fi < FI; ++fi)
#pragma unroll
        for (int fj = 0; fj < FJ; ++fj)
          acc[fi][fj] = __builtin_amdgcn_mfma_f32_16x16x32_bf16(
              af[fi], bfr[fj], acc[fi][fj], 0, 0, 0);
    }
    __syncthreads();
  }

  if (MODE == 4) {
    static_assert(MODE != 4 || FJ == 4, "RoPE epilogue needs 64-col wave span");
    short* Cs = (short*)Cb;
    const bool isqk = (tileN + wc) < 2048;
#pragma unroll
    for (int fi = 0; fi < FI; ++fi) {
#pragma unroll
      for (int fj = 0; fj < FJ; ++fj) {
#pragma unroll
        for (int r = 0; r < 4; ++r) {
          const int row = tileM + wr + fi * 16 + lg * 4 + r;
          const int col = tileN + wc + fj * 16 + l15;
          float a0 = acc[fi][fj][r] + p.bias[col];
          float vout;
          if (isqk) {
            float a1 = acc[fi][fj ^ 2][r] + p.bias[col ^ 32];
            const int dl = fj * 16 + l15;
            const float c = p.cosb[(size_t)row * HDm + dl];
            const float sn = p.sinb[(size_t)row * HDm + dl];
            vout = (fj < 2) ? (a0 * c - a1 * sn) : (a0 * c + a1 * sn);
          } else {
            vout = a0;
          }
          Cs[(size_t)row * p.ldc + col] = f2bf(vout);
        }
      }
    }
    return;
  }

#pragma unroll
  for (int fi = 0; fi < FI; ++fi) {
#pragma unroll
    for (int fj = 0; fj < FJ; ++fj) {
#pragma unroll
      for (int r = 0; r < 4; ++r) {
        const int row = tileM + wr + fi * 16 + lg * 4 + r;
        const int col = tileN + wc + fj * 16 + l15;
        float v = acc[fi][fj][r] * p.scale;
        if (MODE == 5) {
          v += p.bias[col];
          v = 0.5f * v * (1.0f + erff(v * 0.70710678118654752f));
        }
        if (MODE == 2 || MODE == 5 || MODE == 6)
          reinterpret_cast<short*>(Cb)[(size_t)row * p.ldc + col] = f2bf(v);
        else
          reinterpret_cast<float*>(Cb)[(size_t)row * p.ldc + col] = v;
      }
    }
  }
}

extern "C" void kernel_launch(void* const* d_in, const int* in_sizes, int n_in,
                              void* d_out, int out_size, void* d_ws, size_t ws_size,
                              hipStream_t stream) {
  const float* x0 = (const float*)d_in[0];
  const float* cosb = (const float*)d_in[2];
  const float* sinb = (const float*)d_in[3];
  const float* ln1_g = (const float*)d_in[4];
  const float* ln1_b = (const float*)d_in[5];
  const float* qkv_w = (const float*)d_in[6];
  const float* qkv_b = (const float*)d_in[7];
  const float* proj_w = (const float*)d_in[8];
  const float* proj_b = (const float*)d_in[9];
  const float* ln2_g = (const float*)d_in[10];
  const float* ln2_b = (const float*)d_in[11];
  const float* fc1_w = (const float*)d_in[12];
  const float* fc1_b = (const float*)d_in[13];
  const float* fc2_w = (const float*)d_in[14];
  const float* fc2_b = (const float*)d_in[15];

  char* ws = (char*)d_ws;
  size_t off = 0;
  auto alloc = [&](size_t bytes) {
    void* p = ws + off;
    off += (bytes + 255) & ~(size_t)255;
    return p;
  };
  short* wqkvT = (short*)alloc((size_t)2 * 3072 * 1024 * 2);
  short* wprojT = (short*)alloc((size_t)2 * 1024 * 1024 * 2);
  short* wfc1T = (short*)alloc((size_t)2 * 4096 * 1024 * 2);
  short* wfc2T = (short*)alloc((size_t)2 * 1024 * 4096 * 2);
  float* xbuf = (float*)alloc((size_t)Sn * Dm * 4);
  short* hbuf = (short*)alloc((size_t)Sn * Dm * 2);
  short* qkvb = (short*)alloc((size_t)Sn * 3 * Dm * 2);
  short* probs = (short*)alloc((size_t)64 * SEG * SEG * 2);
  // scores fp32 (67MB); also split-K partial space (disjoint lifetimes):
  // proj fp32 2x8.4MB, fc2 bf16 4x4.2MB.
  float* scores = (float*)alloc((size_t)64 * SEG * SEG * 4);
  float* pbuf = scores;
  short* pbufS = (short*)scores;
  short* ao = (short*)alloc((size_t)Sn * Dm * 2);
  short* ffn = (short*)alloc((size_t)Sn * FFm * 2);
  short* vT = ffn;  // vT (4.2MB) aliases ffn: dead during attention phase
  (void)ws_size; (void)in_sizes; (void)n_in; (void)out_size;

  for (int i = 0; i < 2; ++i) {
    wt_kernel<<<dim3(96, 32), 256, 0, stream>>>(
        qkv_w + (size_t)i * Dm * 3072, wqkvT + (size_t)i * 3072 * Dm, Dm, 3072, 3072);
    wt_kernel<<<dim3(32, 32), 256, 0, stream>>>(
        proj_w + (size_t)i * Dm * Dm, wprojT + (size_t)i * Dm * Dm, Dm, Dm, Dm);
    wt_kernel<<<dim3(128, 32), 256, 0, stream>>>(
        fc1_w + (size_t)i * Dm * FFm, wfc1T + (size_t)i * FFm * Dm, Dm, FFm, FFm);
    wt_kernel<<<dim3(32, 128), 256, 0, stream>>>(
        fc2_w + (size_t)i * FFm * Dm, wfc2T + (size_t)i * Dm * FFm, FFm, Dm, Dm);
  }

  // layer 0 LN1 (layer-boundary LNs are fused into the reduces)
  ln_kernel<<<dim3(Sn), 256, 0, stream>>>(x0, ln1_g, ln1_b, hbuf);

  for (int i = 0; i < 2; ++i) {
    const float* xin = i ? (const float*)xbuf : x0;

    {  // qkvb = rope(h @ Wqkv + b)  (64x128, grid 768 = 3/CU, bf16 out)
      GemmArgs p = {};
      p.A = hbuf; p.lda = Dm;
      p.B = wqkvT + (size_t)i * 3072 * Dm; p.ldb = Dm;
      p.C = qkvb; p.ldc = 3 * Dm;
      p.M = Sn; p.N = 3 * Dm; p.K = Dm;
      p.bias = qkv_b + i * 3 * Dm; p.cosb = cosb; p.sinb = sinb; p.scale = 1.0f;
      gemm6<64, 128, 1, 4><<<dim3(24, 32, 1), 256, 0, stream>>>(p);
    }

    // v (bf16 cols 2048.. of qkvb) -> vT
    wtb_kernel<<<dim3(32, 64), 256, 0, stream>>>(qkvb + 2 * Dm, vT, Sn, Dm, 3 * Dm);

    {  // scores = scale * q @ k^T  per (head, seg)  (fp32 out)
      GemmArgs p = {};
      p.A = qkvb; p.lda = 3 * Dm;
      p.B = qkvb + Dm; p.ldb = 3 * Dm;
      p.C = scores; p.ldc = SEG;
      p.M = SEG; p.N = SEG; p.K = HDm; p.scale = 0.125f;
      gemm6<128, 128, 1, 1><<<dim3(4, 4, 64), 256, 0, stream>>>(p);
    }

    softmax_kernel<<<dim3(SEG, 64), 128, 0, stream>>>(scores, probs);

    {  // ao = probs @ V  per (head, seg)  (bf16 out)
      GemmArgs p = {};
      p.A = probs; p.lda = SEG;
      p.B = vT; p.ldb = Sn;
      p.C = ao; p.ldc = Dm;
      p.M = SEG; p.N = HDm; p.K = SEG; p.scale = 1.0f;
      gemm6<64, 64, 1, 2><<<dim3(1, 8, 64), 256, 0, stream>>>(p);
    }

    {  // proj partials = ao @ Wproj  (64x64 split-K=2, fp32, grid 1024)
      GemmArgs p = {};
      p.A = ao; p.lda = Dm;
      p.B = wprojT + (size_t)i * Dm * Dm; p.ldb = Dm;
      p.C = pbuf; p.ldc = Dm;
      p.M = Sn; p.N = Dm; p.K = Dm; p.scale = 1.0f;
      gemm6<64, 64, 2, 3><<<dim3(16, 32, 2), 256, 0, stream>>>(p);
    }
    // x = xin + proj + bias ; h = LN2(x)
    redln_kernel<2><<<dim3(Sn), 256, 0, stream>>>(
        pbuf, proj_b + i * Dm, xin, ln2_g + i * Dm, ln2_b + i * Dm, xbuf, hbuf);

    {  // ffn = gelu(h2 @ Wfc1 + b)  (64x128, grid 1024 = 4/CU, bf16 out)
      GemmArgs p = {};
      p.A = hbuf; p.lda = Dm;
      p.B = wfc1T + (size_t)i * FFm * Dm; p.ldb = Dm;
      p.C = ffn; p.ldc = FFm;
      p.M = Sn; p.N = FFm; p.K = Dm;
      p.bias = fc1_b + i * FFm; p.scale = 1.0f;
      gemm6<64, 128, 1, 5><<<dim3(32, 32, 1), 256, 0, stream>>>(p);
    }

    {  // fc2 partials = ffn @ Wfc2  (64x128 split-K=4, bf16, grid 1024)
      GemmArgs p = {};
      p.A = ffn; p.lda = FFm;
      p.B = wfc2T + (size_t)i * Dm * FFm; p.ldb = FFm;
      p.C = pbufS; p.ldc = Dm;
      p.M = Sn; p.N = Dm; p.K = FFm; p.scale = 1.0f;
      gemm6<64, 128, 4, 6><<<dim3(8, 32, 4), 256, 0, stream>>>(p);
    }
    if (i == 0) {
      // x = xbuf + fc2 + bias ; h = LN1[1](x)
      redln_bf<4><<<dim3(Sn), 256, 0, stream>>>(
          pbufS, fc2_b, xbuf, ln1_g + Dm, ln1_b + Dm, xbuf, hbuf);
    } else {
      fcred_bf<4><<<dim3(Sn * Dm / 1024), 256, 0, stream>>>(
          pbufS, fc2_b + Dm, xbuf, (float*)d_out);
    }
  }
}